// Round 18
// baseline (434.047 us; speedup 1.0000x reference)
//
#include <hip/hip_runtime.h>
#include <cstdint>

#define B_SZ   2048
#define T_SZ   80
#define VOCABN 80
#define EMBN   8
#define HID    256
#define G4     1024
#define NTHR   512
#define HP     272        // int8 h-tile row pitch (16B-aligned, odd 16B blocks)

typedef __bf16 bf16;
typedef __attribute__((ext_vector_type(4))) int    i32x4;
typedef __attribute__((ext_vector_type(4))) float  f32x4;
typedef __attribute__((ext_vector_type(4))) unsigned short u16x4;

__device__ __forceinline__ float sigf(float x) {
    return __builtin_amdgcn_rcpf(1.0f + __expf(-x));
}
__device__ __forceinline__ float tanhf2(float x) {
    return 1.0f - 2.0f * __builtin_amdgcn_rcpf(__expf(2.0f * x) + 1.0f);
}

__device__ __forceinline__ unsigned short f2bf(float f) {
    union { float f; unsigned int u; } v; v.f = f;
    unsigned int u = v.u;
    return (unsigned short)((u + 0x7FFFu + ((u >> 16) & 1u)) >> 16);
}
__device__ __forceinline__ float bf2f(unsigned short h) {
    union { unsigned int u; float f; } v; v.u = ((unsigned int)h) << 16;
    return v.f;
}
__device__ __forceinline__ signed char q8(float h) {
    int q = (int)rintf(h * 127.0f);
    q = q > 127 ? 127 : (q < -127 ? -127 : q);
    return (signed char)q;
}

// LDS-only barrier (R17-proven): no vmcnt(0) drain.
#define BARL do {                                                   \
    __builtin_amdgcn_sched_barrier(0);                              \
    asm volatile("s_waitcnt lgkmcnt(0)" ::: "memory");              \
    __builtin_amdgcn_s_barrier();                                   \
    __builtin_amdgcn_sched_barrier(0);                              \
} while (0)

// ===================== ws layout =====================
#define WP8_OFF  0ull                       // 786432 B
#define EG2_OFF  786432ull                  // 327680 B  eg2[tok][256][4] f32 (emb@W1x + b1)
#define SW_OFF   1114112ull                 // 12288 B   sw[3][1024] f32 column scales
#define C1G_OFF  1126400ull                 // 2 MB  c1 f32 [2048][256]
#define C2G_OFF  3223552ull                 // 2 MB  c2 f32
#define H2P_OFF  5320704ull                 // 512 KB h2 int8 [2048][256]
#define H1C_OFF  5844992ull                 // TC*512KB h1c int8 [b][dt][256]
#define FIXED_WS 5844992ull
#define PER_TC   4718592ull                 // 512KB h1c + 4MB gxc(bf16) per t
#define GX_SLACK 4194304ull                 // +1 step of gxc for branchless prefetch

// ===================== prep kernels (R12-verbatim, proven) =====================
__global__ void prep_scale(const float* __restrict__ W1, const float* __restrict__ W2,
                           float* __restrict__ sw) {
    int idx = blockIdx.x * blockDim.x + threadIdx.x;
    if (idx >= 3 * 1024) return;
    int s = idx >> 10, c = idx & 1023;
    float m = 0.0f;
    for (int r = 0; r < 256; ++r) {
        float v = (s == 0) ? W1[(EMBN + r) * G4 + c]
                : (s == 1) ? W2[r * G4 + c]
                           : W2[(256 + r) * G4 + c];
        m = fmaxf(m, fabsf(v));
    }
    sw[idx] = m * (1.0f / 127.0f) + 1e-20f;
}

__global__ void prep_pack(const float* __restrict__ W1, const float* __restrict__ W2,
                          const float* __restrict__ sw, signed char* __restrict__ wp8) {
    int idx = blockIdx.x * blockDim.x + threadIdx.x;
    if (idx >= 3 * 4 * 64 * 64) return;
    int lane = idx & 63, nt = (idx >> 6) & 63, ks = (idx >> 12) & 3, s = idx >> 14;
    int lc = lane & 15, lg = lane >> 4;
    int scol = (nt & 3) * 256 + (nt >> 3) * 32 + ((nt >> 2) & 1) * 16 + lc;
    float sc = 1.0f / sw[s * 1024 + scol];
#pragma unroll
    for (int e = 0; e < 16; ++e) {
        int row = ks * 64 + lg * 16 + e;
        float v = (s == 0) ? W1[(EMBN + row) * G4 + scol]
                : (s == 1) ? W2[row * G4 + scol]
                           : W2[(256 + row) * G4 + scol];
        int q = (int)rintf(v * sc);
        q = q > 127 ? 127 : (q < -127 ? -127 : q);
        wp8[(size_t)idx * 16 + e] = (signed char)q;
    }
}

__global__ void prep_eg2(const float* __restrict__ emb, const float* __restrict__ W1,
                         const float* __restrict__ b1, float* __restrict__ eg2) {
    int idx = blockIdx.x * blockDim.x + threadIdx.x;
    if (idx >= VOCABN * 256) return;
    int v = idx >> 8, h = idx & 255;
#pragma unroll
    for (int g = 0; g < 4; ++g) {
        int c = g * 256 + h;
        float s = b1[c];
#pragma unroll
        for (int e = 0; e < EMBN; ++e) s += emb[v * EMBN + e] * W1[e * G4 + c];
        eg2[(size_t)idx * 4 + g] = s;
    }
}

// ===================== kernel A: layer-1 recurrence (R17-verbatim) =====================
__global__ __launch_bounds__(NTHR, 2)
void lstm_l1(const int* __restrict__ feat,
             const signed char* __restrict__ wp8A, const float* __restrict__ swA,
             const float* __restrict__ eg2,
             signed char* __restrict__ h1c, float* __restrict__ c1g,
             int t0, int TC)
{
    __shared__ __align__(16) signed char wlds[2][64][1024];   // ks 2,3: 128 KB
    __shared__ __align__(16) signed char h1s[2][16 * HP];     // 8.5 KB (rows 8..15 stay 0)
    __shared__ unsigned char toks8[8 * T_SZ];

    const int tid  = threadIdx.x;
    const int lane = tid & 63;
    const int wid  = tid >> 6;
    const int lc   = lane & 15;
    const int lg   = lane >> 4;
    const int hfl  = lg >> 1;
    const int lgl  = lg & 1;
    const int bblk = blockIdx.x;
    const int b0   = bblk * 8;
    const int t1   = t0 + TC;

    for (int i = tid; i < 2 * 16 * HP; i += NTHR) h1s[0][i] = 0;
    for (int i = tid; i < 8 * T_SZ; i += NTHR) {
        int r = i / T_SZ, t = i - r * T_SZ;
        toks8[i] = (unsigned char)feat[(b0 + r) * T_SZ + t];
    }
    for (int i = tid; i < 2 * 64 * 64; i += NTHR)
        *(i32x4*)&wlds[0][0][(size_t)i * 16] =
            *(const i32x4*)&wp8A[(size_t)(2 * 64 * 64 + i) * 16];

    const int hcolp = wid * 32 + hfl * 16 + lc;
    float c1[4] = {0.f, 0.f, 0.f, 0.f};
    if (t0 > 0) {
        __syncthreads();
        for (int i = tid; i < 8 * 256; i += NTHR) {
            int row = i >> 8, col = i & 255;
            h1s[0][row * HP + col] = h1c[((size_t)(b0 + row) * TC + (TC - 1)) * 256 + col];
        }
#pragma unroll
        for (int r = 0; r < 4; ++r)
            c1[r] = c1g[(size_t)(b0 + lgl * 4 + r) * 256 + hcolp];
    }
    __syncthreads();

    i32x4 wreg[16];
#pragma unroll
    for (int ks = 0; ks < 2; ++ks)
#pragma unroll
        for (int j = 0; j < 8; ++j)
            wreg[ks * 8 + j] = *(const i32x4*)&wp8A[(size_t)((ks * 64 + wid * 8 + j) * 64 + lane) * 16];

    float ssv[4];
#pragma unroll
    for (int g = 0; g < 4; ++g)
        ssv[g] = swA[g * 256 + hcolp] * (1.0f / 127.0f);

    const i32x4 zi = {0, 0, 0, 0};

    for (int t = t0; t < t1; ++t) {
        const int rb_ = t & 1;
        const signed char* hr = h1s[rb_];
        signed char* hw = h1s[rb_ ^ 1];

        f32x4 e4r[4];
#pragma unroll
        for (int r = 0; r < 4; ++r) {
            const int row = lgl * 4 + r;
            const int tok = toks8[row * T_SZ + t];
            e4r[r] = *(const f32x4*)&eg2[((size_t)tok * 256 + hcolp) * 4];
        }

        i32x4 ia0[4], ia1[4];
#pragma unroll
        for (int g = 0; g < 4; ++g) { ia0[g] = zi; ia1[g] = zi; }
#pragma unroll
        for (int ks = 0; ks < 4; ++ks) {
            i32x4 afr = *(const i32x4*)&hr[lc * HP + ks * 64 + lg * 16];
#pragma unroll
            for (int g = 0; g < 4; ++g) {
                i32x4 w0 = (ks < 2) ? wreg[ks * 8 + g]
                         : *(const i32x4*)&wlds[ks - 2][wid * 8 + g][(size_t)lane * 16];
                ia0[g] = __builtin_amdgcn_mfma_i32_16x16x64_i8(afr, w0, ia0[g], 0, 0, 0);
                i32x4 w1 = (ks < 2) ? wreg[ks * 8 + 4 + g]
                         : *(const i32x4*)&wlds[ks - 2][wid * 8 + 4 + g][(size_t)lane * 16];
                ia1[g] = __builtin_amdgcn_mfma_i32_16x16x64_i8(afr, w1, ia1[g], 0, 0, 0);
            }
        }
        float gvv[4][4];
#pragma unroll
        for (int g = 0; g < 4; ++g)
#pragma unroll
            for (int r = 0; r < 4; ++r) {
                int v1  = __shfl(ia1[g][r], lane & 31);
                int sel = hfl ? v1 : ia0[g][r];
                gvv[g][r] = ssv[g] * (float)sel + e4r[r][g];
            }
#pragma unroll
        for (int r = 0; r < 4; ++r) {
            const int row = lgl * 4 + r;
            float cn = c1[r] * sigf(gvv[2][r] + 1.0f) + sigf(gvv[0][r]) * tanhf2(gvv[1][r]);
            float h  = tanhf2(cn) * sigf(gvv[3][r]);
            c1[r] = cn;
            signed char qv = q8(h);
            hw[row * HP + hcolp] = qv;
            h1c[((size_t)(b0 + row) * TC + (t - t0)) * 256 + hcolp] = qv;
        }
        BARL;
    }
    if (t1 < T_SZ) {
#pragma unroll
        for (int r = 0; r < 4; ++r)
            c1g[(size_t)(b0 + lgl * 4 + r) * 256 + hcolp] = c1[r];
    }
}

// ===================== kernel G: gxc = h1c @ W2x + b2 (R12-verbatim) =====================
__global__ __launch_bounds__(NTHR, 2)
void gx_gemm(const signed char* __restrict__ h1c,
             const signed char* __restrict__ wp8G, const float* __restrict__ swG,
             const float* __restrict__ b2, unsigned short* __restrict__ gxc, int TC)
{
    __shared__ __align__(16) signed char wlds[2][64][1024];
    __shared__ __align__(16) signed char hbuf[16 * HP];

    const int tid  = threadIdx.x;
    const int lane = tid & 63;
    const int wid  = tid >> 6;
    const int lc   = lane & 15;
    const int lg   = lane >> 4;
    const int bblk = blockIdx.x;

    for (int i = tid; i < 2 * 64 * 64; i += NTHR)
        *(i32x4*)&wlds[0][0][(size_t)i * 16] =
            *(const i32x4*)&wp8G[(size_t)(2 * 64 * 64 + i) * 16];

    i32x4 wreg[16];
#pragma unroll
    for (int ks = 0; ks < 2; ++ks)
#pragma unroll
        for (int j = 0; j < 8; ++j)
            wreg[ks * 8 + j] = *(const i32x4*)&wp8G[(size_t)((ks * 64 + wid * 8 + j) * 64 + lane) * 16];

    float ssg[8], b2v[8];
#pragma unroll
    for (int j = 0; j < 8; ++j) {
        int scol = (j & 3) * 256 + wid * 32 + ((j >> 2) & 1) * 16 + lc;
        ssg[j] = swG[scol] * (1.0f / 127.0f);
        b2v[j] = b2[scol];
    }

    const i32x4 zi = {0, 0, 0, 0};
    const int m    = tid >> 5;
    const int col0 = (tid & 31) * 8;
    const int np   = TC >> 1;

    unsigned long long sreg =
        *(const unsigned long long*)&h1c[((size_t)(bblk * 8 + (m >> 1)) * TC + (m & 1)) * 256 + col0];

    for (int tt = 0; tt < np; ++tt) {
        __syncthreads();
        *(unsigned long long*)&hbuf[m * HP + col0] = sreg;
        __syncthreads();
        if (tt + 1 < np)
            sreg = *(const unsigned long long*)
                &h1c[((size_t)(bblk * 8 + (m >> 1)) * TC + (tt + 1) * 2 + (m & 1)) * 256 + col0];

        i32x4 acc[8];
#pragma unroll
        for (int j = 0; j < 8; ++j) acc[j] = zi;
#pragma unroll
        for (int ks = 0; ks < 4; ++ks) {
            i32x4 afr = *(const i32x4*)&hbuf[lc * HP + ks * 64 + lg * 16];
#pragma unroll
            for (int j = 0; j < 8; ++j) {
                i32x4 w = (ks < 2) ? wreg[ks * 8 + j]
                        : *(const i32x4*)&wlds[ks - 2][wid * 8 + j][(size_t)lane * 16];
                acc[j] = __builtin_amdgcn_mfma_i32_16x16x64_i8(afr, w, acc[j], 0, 0, 0);
            }
        }
#pragma unroll
        for (int j = 0; j < 8; ++j) {
            const int nt = wid * 8 + j;
#pragma unroll
            for (int r = 0; r < 4; ++r) {
                size_t addr = ((((size_t)bblk * TC + tt * 2 + (r & 1)) * 64 + nt) * 16 + lc) * 8
                              + 2 * lg + (r >> 1);
                gxc[addr] = f2bf(ssg[j] * (float)acc[j][r] + b2v[j]);
            }
        }
    }
}

// ===================== kernel B: layer-2 (depth-1 gx prefetch, ping-pong, branchless) =====================
// One step body; GXU = u16x4 set consumed this step, GXP = set filled by prefetch for next step.
#define L2STEP(tt_, GXU, GXP) do {                                              \
    const signed char* hr = h2s[(tt_) & 1];                                     \
    signed char* hw = h2s[((tt_) & 1) ^ 1];                                     \
    _Pragma("unroll")                                                           \
    for (int g = 0; g < 4; ++g) { GXP[g] = *(const u16x4*)pg[g]; pg[g] += 8192; } \
    i32x4 ia0[4], ia1[4];                                                       \
    _Pragma("unroll")                                                           \
    for (int g = 0; g < 4; ++g) { ia0[g] = zi; ia1[g] = zi; }                   \
    _Pragma("unroll")                                                           \
    for (int ks = 0; ks < 4; ++ks) {                                            \
        i32x4 afr = *(const i32x4*)&hr[lc * HP + ks * 64 + lg * 16];            \
        _Pragma("unroll")                                                       \
        for (int g = 0; g < 4; ++g) {                                           \
            i32x4 w0 = (ks < 2) ? wreg[ks * 8 + g]                              \
                     : *(const i32x4*)&wlds[ks - 2][wid * 8 + g][(size_t)lane * 16]; \
            ia0[g] = __builtin_amdgcn_mfma_i32_16x16x64_i8(afr, w0, ia0[g], 0, 0, 0); \
            i32x4 w1 = (ks < 2) ? wreg[ks * 8 + 4 + g]                          \
                     : *(const i32x4*)&wlds[ks - 2][wid * 8 + 4 + g][(size_t)lane * 16]; \
            ia1[g] = __builtin_amdgcn_mfma_i32_16x16x64_i8(afr, w1, ia1[g], 0, 0, 0); \
        }                                                                       \
    }                                                                           \
    float gvv[4][4];                                                            \
    _Pragma("unroll")                                                           \
    for (int g = 0; g < 4; ++g)                                                 \
        _Pragma("unroll")                                                       \
        for (int r = 0; r < 4; ++r) {                                           \
            int v1  = __shfl(ia1[g][r], lane & 31);                             \
            int sel = hfl ? v1 : ia0[g][r];                                     \
            gvv[g][r] = ssv[g] * (float)sel + bf2f(GXU[g][r]);                  \
        }                                                                       \
    _Pragma("unroll")                                                           \
    for (int r = 0; r < 4; ++r) {                                               \
        const int row = lgl * 4 + r;                                            \
        float cn = c2[r] * sigf(gvv[2][r] + 1.0f) + sigf(gvv[0][r]) * tanhf2(gvv[1][r]); \
        float h  = tanhf2(cn) * sigf(gvv[3][r]);                                \
        c2[r] = cn;                                                             \
        hw[row * HP + hcolp] = q8(h);                                           \
    }                                                                           \
    BARL;                                                                       \
} while (0)

__global__ __launch_bounds__(NTHR, 2)
void lstm_l2(const signed char* __restrict__ wp8B, const float* __restrict__ swB,
             const unsigned short* __restrict__ gxc,
             const int* __restrict__ labels,
             const float* __restrict__ Wd, const float* __restrict__ bd,
             float* __restrict__ out, float* __restrict__ c2g,
             signed char* __restrict__ h2p, int t0, int TC)
{
    __shared__ __align__(16) signed char wlds[2][64][1024];   // 128 KB
    __shared__ __align__(16) signed char h2s[2][16 * HP];     // 8.5 KB
    __shared__ float logitb[8][VOCABN + 1];
    __shared__ float lossb[8];

    const int tid  = threadIdx.x;
    const int lane = tid & 63;
    const int wid  = tid >> 6;
    const int lc   = lane & 15;
    const int lg   = lane >> 4;
    const int hfl  = lg >> 1;
    const int lgl  = lg & 1;
    const int bblk = blockIdx.x;
    const int b0   = bblk * 8;
    const int t1   = t0 + TC;

    for (int i = tid; i < 2 * 16 * HP; i += NTHR) h2s[0][i] = 0;
    for (int i = tid; i < 2 * 64 * 64; i += NTHR)
        *(i32x4*)&wlds[0][0][(size_t)i * 16] =
            *(const i32x4*)&wp8B[(size_t)(2 * 64 * 64 + i) * 16];

    const int hcolp = wid * 32 + hfl * 16 + lc;
    float c2[4] = {0.f, 0.f, 0.f, 0.f};
    if (t0 > 0) {
        __syncthreads();
        for (int i = tid; i < 8 * 256; i += NTHR) {
            int row = i >> 8, col = i & 255;
            h2s[0][row * HP + col] = h2p[(size_t)(b0 + row) * 256 + col];
        }
#pragma unroll
        for (int r = 0; r < 4; ++r)
            c2[r] = c2g[(size_t)(b0 + lgl * 4 + r) * 256 + hcolp];
    }
    __syncthreads();

    i32x4 wreg[16];
#pragma unroll
    for (int ks = 0; ks < 2; ++ks)
#pragma unroll
        for (int j = 0; j < 8; ++j)
            wreg[ks * 8 + j] = *(const i32x4*)&wp8B[(size_t)((ks * 64 + wid * 8 + j) * 64 + lane) * 16];

    float ssv[4];
#pragma unroll
    for (int g = 0; g < 4; ++g)
        ssv[g] = swB[g * 256 + hcolp] * (1.0f / 127.0f);

    // gx pointers, advance 8192 ushorts per step (prefetch reads step t, then bumps)
    const unsigned short* pg[4];
#pragma unroll
    for (int g = 0; g < 4; ++g) {
        const int nt = wid * 8 + hfl * 4 + g;
        pg[g] = gxc + (((size_t)bblk * TC * 64 + nt) * 16 + lc) * 8 + 4 * lgl;
    }

    // prologue: load gx for first (even) step into A set
    u16x4 gxA[4], gxB[4];
#pragma unroll
    for (int g = 0; g < 4; ++g) { gxA[g] = *(const u16x4*)pg[g]; pg[g] += 8192; }

    const i32x4 zi = {0, 0, 0, 0};

    // TC is even: process pairs; branchless prefetch (last read lands in +1-step slack)
    for (int tp = 0; tp < (TC >> 1); ++tp) {
        const int te = tp * 2;
        L2STEP(te,     gxA, gxB);   // even step: consume A, prefetch B
        L2STEP(te + 1, gxB, gxA);   // odd  step: consume B, prefetch A
    }

    if (t1 < T_SZ) {
#pragma unroll
        for (int r = 0; r < 4; ++r)
            c2g[(size_t)(b0 + lgl * 4 + r) * 256 + hcolp] = c2[r];
        for (int i = tid; i < 8 * 256; i += NTHR) {
            int row = i >> 8, col = i & 255;
            h2p[(size_t)(b0 + row) * 256 + col] = h2s[0][row * HP + col];
        }
        return;
    }

    // ---- loss epilogue (final chunk): final h2 in h2s[0] (t1 even) ----
    const signed char* h2fin = h2s[0];
    for (int pp = tid; pp < 8 * VOCABN; pp += NTHR) {
        int row = pp / VOCABN, v = pp - row * VOCABN;
        float s = bd[v];
        for (int k = 0; k < HID; ++k)
            s += ((float)h2fin[row * HP + k] * (1.0f / 127.0f)) * Wd[k * VOCABN + v];
        logitb[row][v] = s;
    }
    __syncthreads();
    if (tid < 8) {
        float mx = -1e30f;
        for (int v = 0; v < VOCABN; ++v) mx = fmaxf(mx, logitb[tid][v]);
        float s = 0.f;
        for (int v = 0; v < VOCABN; ++v) s += __expf(logitb[tid][v] - mx);
        int lab = labels[b0 + tid];
        lossb[tid] = mx + __logf(s) - logitb[tid][lab];
    }
    __syncthreads();
    if (tid == 0) {
        float s = 0.f;
#pragma unroll
        for (int r = 0; r < 8; ++r) s += lossb[r];
        atomicAdd(out, s * (1.0f / (float)B_SZ));
    }
}

// ===================== launch =====================
extern "C" void kernel_launch(void* const* d_in, const int* in_sizes, int n_in,
                              void* d_out, int out_size, void* d_ws, size_t ws_size,
                              hipStream_t stream)
{
    (void)in_sizes; (void)n_in; (void)out_size;
    const int*   feat   = (const int*)d_in[0];
    const int*   labels = (const int*)d_in[1];
    const float* emb    = (const float*)d_in[2];
    const float* W1     = (const float*)d_in[3];
    const float* b1     = (const float*)d_in[4];
    const float* W2     = (const float*)d_in[5];
    const float* b2     = (const float*)d_in[6];
    const float* Wd     = (const float*)d_in[7];
    const float* bd     = (const float*)d_in[8];
    float* out = (float*)d_out;
    char* ws = (char*)d_ws;

    (void)hipMemsetAsync(d_out, 0, sizeof(float), stream);

    int TC = 2;
    {
        const int tcs[8] = {80, 40, 20, 16, 10, 8, 4, 2};
        for (int i = 0; i < 8; ++i)
            if (FIXED_WS + (size_t)tcs[i] * PER_TC + GX_SLACK <= ws_size) { TC = tcs[i]; break; }
    }

    signed char* wp8  = (signed char*)(ws + WP8_OFF);
    float*       eg2  = (float*)(ws + EG2_OFF);
    float*       sw   = (float*)(ws + SW_OFF);
    float*       c1g  = (float*)(ws + C1G_OFF);
    float*       c2g  = (float*)(ws + C2G_OFF);
    signed char* h2p  = (signed char*)(ws + H2P_OFF);
    signed char* h1c  = (signed char*)(ws + H1C_OFF);
    unsigned short* gxc = (unsigned short*)(ws + H1C_OFF + (size_t)TC * 524288ull);

    const signed char* wp8A = wp8;                       // W1h
    const signed char* wp8G = wp8 + 262144;              // W2x
    const signed char* wp8B = wp8 + 524288;              // W2h
    const float* swA = sw;
    const float* swG = sw + 1024;
    const float* swB = sw + 2048;

    prep_scale<<<(3 * 1024 + 255) / 256, 256, 0, stream>>>(W1, W2, sw);
    prep_pack<<<(3 * 4 * 64 * 64 + 255) / 256, 256, 0, stream>>>(W1, W2, sw, wp8);
    prep_eg2<<<(VOCABN * 256 + 255) / 256, 256, 0, stream>>>(emb, W1, b1, eg2);

    for (int t0 = 0; t0 < T_SZ; t0 += TC) {
        lstm_l1<<<256, NTHR, 0, stream>>>(feat, wp8A, swA, eg2, h1c, c1g, t0, TC);
        gx_gemm<<<256, NTHR, 0, stream>>>(h1c, wp8G, swG, b2, gxc, TC);
        lstm_l2<<<256, NTHR, 0, stream>>>(wp8B, swB, gxc, labels, Wd, bd,
                                          out, c2g, h2p, t0, TC);
    }
}

// Round 19
// 425.099 us; speedup vs baseline: 1.0210x; 1.0210x over previous
//
#include <hip/hip_runtime.h>
#include <cstdint>

#define B_SZ   2048
#define T_SZ   80
#define VOCABN 80
#define EMBN   8
#define HID    256
#define G4     1024
#define NTHR   512
#define HP     272        // int8 h-tile row pitch (16B-aligned, odd 16B blocks)

typedef __bf16 bf16;
typedef __attribute__((ext_vector_type(4))) int    i32x4;
typedef __attribute__((ext_vector_type(4))) float  f32x4;
typedef __attribute__((ext_vector_type(4))) unsigned short u16x4;

__device__ __forceinline__ float sigf(float x) {
    return __builtin_amdgcn_rcpf(1.0f + __expf(-x));
}
__device__ __forceinline__ float tanhf2(float x) {
    return 1.0f - 2.0f * __builtin_amdgcn_rcpf(__expf(2.0f * x) + 1.0f);
}

__device__ __forceinline__ unsigned short f2bf(float f) {
    union { float f; unsigned int u; } v; v.f = f;
    unsigned int u = v.u;
    return (unsigned short)((u + 0x7FFFu + ((u >> 16) & 1u)) >> 16);
}
__device__ __forceinline__ float bf2f(unsigned short h) {
    union { unsigned int u; float f; } v; v.u = ((unsigned int)h) << 16;
    return v.f;
}
// q8 with float clamp (v_med3_f32) then round+cvt
__device__ __forceinline__ signed char q8(float h) {
    float hc = fminf(fmaxf(h * 127.0f, -127.0f), 127.0f);
    return (signed char)(int)rintf(hc);
}

// LDS-only barrier (R17-proven): no vmcnt(0) drain.
#define BARL do {                                                   \
    __builtin_amdgcn_sched_barrier(0);                              \
    asm volatile("s_waitcnt lgkmcnt(0)" ::: "memory");              \
    __builtin_amdgcn_s_barrier();                                   \
    __builtin_amdgcn_sched_barrier(0);                              \
} while (0)

// ===================== ws layout =====================
#define WP8_OFF  0ull                       // 786432 B
#define EG2_OFF  786432ull                  // 327680 B  eg2[tok][256][4] f32 (emb@W1x + b1, f-bias folded)
#define SW_OFF   1114112ull                 // 12288 B   sw[3][1024] f32 column scales
#define C1G_OFF  1126400ull                 // 2 MB  c1 f32 [2048][256]
#define C2G_OFF  3223552ull                 // 2 MB  c2 f32
#define H2P_OFF  5320704ull                 // 512 KB h2 int8 [2048][256]
#define H1C_OFF  5844992ull                 // TC*512KB h1c int8 [b][dt][256]
#define FIXED_WS 5844992ull
#define PER_TC   4718592ull                 // 512KB h1c + 4MB gxc(bf16) per t

// ===================== prep kernels =====================
__global__ void prep_scale(const float* __restrict__ W1, const float* __restrict__ W2,
                           float* __restrict__ sw) {
    int idx = blockIdx.x * blockDim.x + threadIdx.x;
    if (idx >= 3 * 1024) return;
    int s = idx >> 10, c = idx & 1023;
    float m = 0.0f;
    for (int r = 0; r < 256; ++r) {
        float v = (s == 0) ? W1[(EMBN + r) * G4 + c]
                : (s == 1) ? W2[r * G4 + c]
                           : W2[(256 + r) * G4 + c];
        m = fmaxf(m, fabsf(v));
    }
    sw[idx] = m * (1.0f / 127.0f) + 1e-20f;
}

__global__ void prep_pack(const float* __restrict__ W1, const float* __restrict__ W2,
                          const float* __restrict__ sw, signed char* __restrict__ wp8) {
    int idx = blockIdx.x * blockDim.x + threadIdx.x;
    if (idx >= 3 * 4 * 64 * 64) return;
    int lane = idx & 63, nt = (idx >> 6) & 63, ks = (idx >> 12) & 3, s = idx >> 14;
    int lc = lane & 15, lg = lane >> 4;
    int scol = (nt & 3) * 256 + (nt >> 3) * 32 + ((nt >> 2) & 1) * 16 + lc;
    float sc = 1.0f / sw[s * 1024 + scol];
#pragma unroll
    for (int e = 0; e < 16; ++e) {
        int row = ks * 64 + lg * 16 + e;
        float v = (s == 0) ? W1[(EMBN + row) * G4 + scol]
                : (s == 1) ? W2[row * G4 + scol]
                           : W2[(256 + row) * G4 + scol];
        int q = (int)rintf(v * sc);
        q = q > 127 ? 127 : (q < -127 ? -127 : q);
        wp8[(size_t)idx * 16 + e] = (signed char)q;
    }
}

// eg2 with FORGET_BIAS folded into gate 2
__global__ void prep_eg2(const float* __restrict__ emb, const float* __restrict__ W1,
                         const float* __restrict__ b1, float* __restrict__ eg2) {
    int idx = blockIdx.x * blockDim.x + threadIdx.x;
    if (idx >= VOCABN * 256) return;
    int v = idx >> 8, h = idx & 255;
#pragma unroll
    for (int g = 0; g < 4; ++g) {
        int c = g * 256 + h;
        float s = b1[c] + ((g == 2) ? 1.0f : 0.0f);
#pragma unroll
        for (int e = 0; e < EMBN; ++e) s += emb[v * EMBN + e] * W1[e * G4 + c];
        eg2[(size_t)idx * 4 + g] = s;
    }
}

// ===================== kernel A: layer-1 recurrence =====================
__global__ __launch_bounds__(NTHR, 2)
void lstm_l1(const int* __restrict__ feat,
             const signed char* __restrict__ wp8A, const float* __restrict__ swA,
             const float* __restrict__ eg2,
             signed char* __restrict__ h1c, float* __restrict__ c1g,
             int t0, int TC)
{
    __shared__ __align__(16) signed char wlds[2][64][1024];   // ks 2,3: 128 KB
    __shared__ __align__(16) signed char h1s[2][16 * HP];     // 8.5 KB (rows 8..15 stay 0)
    __shared__ unsigned char toks8[8 * T_SZ];

    const int tid  = threadIdx.x;
    const int lane = tid & 63;
    const int wid  = tid >> 6;
    const int lc   = lane & 15;
    const int lg   = lane >> 4;
    const int hfl  = lg >> 1;
    const int lgl  = lg & 1;
    const int bblk = blockIdx.x;
    const int b0   = bblk * 8;
    const int t1   = t0 + TC;

    for (int i = tid; i < 2 * 16 * HP; i += NTHR) h1s[0][i] = 0;
    for (int i = tid; i < 8 * T_SZ; i += NTHR) {
        int r = i / T_SZ, t = i - r * T_SZ;
        toks8[i] = (unsigned char)feat[(b0 + r) * T_SZ + t];
    }
    for (int i = tid; i < 2 * 64 * 64; i += NTHR)
        *(i32x4*)&wlds[0][0][(size_t)i * 16] =
            *(const i32x4*)&wp8A[(size_t)(2 * 64 * 64 + i) * 16];

    const int hcolp = wid * 32 + hfl * 16 + lc;
    float c1[4] = {0.f, 0.f, 0.f, 0.f};
    if (t0 > 0) {
        __syncthreads();
        for (int i = tid; i < 8 * 256; i += NTHR) {
            int row = i >> 8, col = i & 255;
            h1s[0][row * HP + col] = h1c[((size_t)(b0 + row) * TC + (TC - 1)) * 256 + col];
        }
#pragma unroll
        for (int r = 0; r < 4; ++r)
            c1[r] = c1g[(size_t)(b0 + lgl * 4 + r) * 256 + hcolp];
    }
    __syncthreads();

    i32x4 wreg[16];
#pragma unroll
    for (int ks = 0; ks < 2; ++ks)
#pragma unroll
        for (int j = 0; j < 8; ++j)
            wreg[ks * 8 + j] = *(const i32x4*)&wp8A[(size_t)((ks * 64 + wid * 8 + j) * 64 + lane) * 16];

    float ssv[4];
#pragma unroll
    for (int g = 0; g < 4; ++g)
        ssv[g] = swA[g * 256 + hcolp] * (1.0f / 127.0f);

    const i32x4 zi = {0, 0, 0, 0};

    for (int t = t0; t < t1; ++t) {
        const int rb_ = t & 1;
        const signed char* hr = h1s[rb_];
        signed char* hw = h1s[rb_ ^ 1];

        f32x4 e4r[4];
#pragma unroll
        for (int r = 0; r < 4; ++r) {
            const int row = lgl * 4 + r;
            const int tok = toks8[row * T_SZ + t];
            e4r[r] = *(const f32x4*)&eg2[((size_t)tok * 256 + hcolp) * 4];
        }

        i32x4 ia0[4], ia1[4];
#pragma unroll
        for (int g = 0; g < 4; ++g) { ia0[g] = zi; ia1[g] = zi; }
#pragma unroll
        for (int ks = 0; ks < 4; ++ks) {
            i32x4 afr = *(const i32x4*)&hr[lc * HP + ks * 64 + lg * 16];
#pragma unroll
            for (int g = 0; g < 4; ++g) {
                i32x4 w0 = (ks < 2) ? wreg[ks * 8 + g]
                         : *(const i32x4*)&wlds[ks - 2][wid * 8 + g][(size_t)lane * 16];
                ia0[g] = __builtin_amdgcn_mfma_i32_16x16x64_i8(afr, w0, ia0[g], 0, 0, 0);
                i32x4 w1 = (ks < 2) ? wreg[ks * 8 + 4 + g]
                         : *(const i32x4*)&wlds[ks - 2][wid * 8 + 4 + g][(size_t)lane * 16];
                ia1[g] = __builtin_amdgcn_mfma_i32_16x16x64_i8(afr, w1, ia1[g], 0, 0, 0);
            }
        }
        float gvv[4][4];
#pragma unroll
        for (int g = 0; g < 4; ++g)
#pragma unroll
            for (int r = 0; r < 4; ++r) {
                int v1  = __shfl(ia1[g][r], lane & 31);
                int sel = hfl ? v1 : ia0[g][r];
                gvv[g][r] = ssv[g] * (float)sel + e4r[r][g];
            }
#pragma unroll
        for (int r = 0; r < 4; ++r) {
            const int row = lgl * 4 + r;
            float cn = c1[r] * sigf(gvv[2][r]) + sigf(gvv[0][r]) * tanhf2(gvv[1][r]);
            float h  = tanhf2(cn) * sigf(gvv[3][r]);
            c1[r] = cn;
            signed char qv = q8(h);
            hw[row * HP + hcolp] = qv;
            h1c[((size_t)(b0 + row) * TC + (t - t0)) * 256 + hcolp] = qv;
        }
        BARL;
    }
    if (t1 < T_SZ) {
#pragma unroll
        for (int r = 0; r < 4; ++r)
            c1g[(size_t)(b0 + lgl * 4 + r) * 256 + hcolp] = c1[r];
    }
}

// ===================== kernel G: gxc = h1c @ W2x + b2 (f-bias folded) =====================
__global__ __launch_bounds__(NTHR, 2)
void gx_gemm(const signed char* __restrict__ h1c,
             const signed char* __restrict__ wp8G, const float* __restrict__ swG,
             const float* __restrict__ b2, unsigned short* __restrict__ gxc, int TC)
{
    __shared__ __align__(16) signed char wlds[2][64][1024];
    __shared__ __align__(16) signed char hbuf[16 * HP];

    const int tid  = threadIdx.x;
    const int lane = tid & 63;
    const int wid  = tid >> 6;
    const int lc   = lane & 15;
    const int lg   = lane >> 4;
    const int bblk = blockIdx.x;

    for (int i = tid; i < 2 * 64 * 64; i += NTHR)
        *(i32x4*)&wlds[0][0][(size_t)i * 16] =
            *(const i32x4*)&wp8G[(size_t)(2 * 64 * 64 + i) * 16];

    i32x4 wreg[16];
#pragma unroll
    for (int ks = 0; ks < 2; ++ks)
#pragma unroll
        for (int j = 0; j < 8; ++j)
            wreg[ks * 8 + j] = *(const i32x4*)&wp8G[(size_t)((ks * 64 + wid * 8 + j) * 64 + lane) * 16];

    float ssg[8], b2v[8];
#pragma unroll
    for (int j = 0; j < 8; ++j) {
        int scol = (j & 3) * 256 + wid * 32 + ((j >> 2) & 1) * 16 + lc;
        ssg[j] = swG[scol] * (1.0f / 127.0f);
        b2v[j] = b2[scol] + (((j & 3) == 2) ? 1.0f : 0.0f);   // fold FORGET_BIAS
    }

    const i32x4 zi = {0, 0, 0, 0};
    const int m    = tid >> 5;
    const int col0 = (tid & 31) * 8;
    const int np   = TC >> 1;

    unsigned long long sreg =
        *(const unsigned long long*)&h1c[((size_t)(bblk * 8 + (m >> 1)) * TC + (m & 1)) * 256 + col0];

    for (int tt = 0; tt < np; ++tt) {
        __syncthreads();
        *(unsigned long long*)&hbuf[m * HP + col0] = sreg;
        __syncthreads();
        if (tt + 1 < np)
            sreg = *(const unsigned long long*)
                &h1c[((size_t)(bblk * 8 + (m >> 1)) * TC + (tt + 1) * 2 + (m & 1)) * 256 + col0];

        i32x4 acc[8];
#pragma unroll
        for (int j = 0; j < 8; ++j) acc[j] = zi;
#pragma unroll
        for (int ks = 0; ks < 4; ++ks) {
            i32x4 afr = *(const i32x4*)&hbuf[lc * HP + ks * 64 + lg * 16];
#pragma unroll
            for (int j = 0; j < 8; ++j) {
                i32x4 w = (ks < 2) ? wreg[ks * 8 + j]
                        : *(const i32x4*)&wlds[ks - 2][wid * 8 + j][(size_t)lane * 16];
                acc[j] = __builtin_amdgcn_mfma_i32_16x16x64_i8(afr, w, acc[j], 0, 0, 0);
            }
        }
#pragma unroll
        for (int j = 0; j < 8; ++j) {
            const int nt = wid * 8 + j;
#pragma unroll
            for (int r = 0; r < 4; ++r) {
                size_t addr = ((((size_t)bblk * TC + tt * 2 + (r & 1)) * 64 + nt) * 16 + lc) * 8
                              + 2 * lg + (r >> 1);
                gxc[addr] = f2bf(ssg[j] * (float)acc[j][r] + b2v[j]);
            }
        }
    }
}

// ===================== kernel B: layer-2 recurrence (+ loss) =====================
__global__ __launch_bounds__(NTHR, 2)
void lstm_l2(const signed char* __restrict__ wp8B, const float* __restrict__ swB,
             const unsigned short* __restrict__ gxc,
             const int* __restrict__ labels,
             const float* __restrict__ Wd, const float* __restrict__ bd,
             float* __restrict__ out, float* __restrict__ c2g,
             signed char* __restrict__ h2p, int t0, int TC)
{
    __shared__ __align__(16) signed char wlds[2][64][1024];   // 128 KB
    __shared__ __align__(16) signed char h2s[2][16 * HP];     // 8.5 KB
    __shared__ float logitb[8][VOCABN + 1];
    __shared__ float lossb[8];

    const int tid  = threadIdx.x;
    const int lane = tid & 63;
    const int wid  = tid >> 6;
    const int lc   = lane & 15;
    const int lg   = lane >> 4;
    const int hfl  = lg >> 1;
    const int lgl  = lg & 1;
    const int bblk = blockIdx.x;
    const int b0   = bblk * 8;
    const int t1   = t0 + TC;

    for (int i = tid; i < 2 * 16 * HP; i += NTHR) h2s[0][i] = 0;
    for (int i = tid; i < 2 * 64 * 64; i += NTHR)
        *(i32x4*)&wlds[0][0][(size_t)i * 16] =
            *(const i32x4*)&wp8B[(size_t)(2 * 64 * 64 + i) * 16];

    const int hcolp = wid * 32 + hfl * 16 + lc;
    float c2[4] = {0.f, 0.f, 0.f, 0.f};
    if (t0 > 0) {
        __syncthreads();
        for (int i = tid; i < 8 * 256; i += NTHR) {
            int row = i >> 8, col = i & 255;
            h2s[0][row * HP + col] = h2p[(size_t)(b0 + row) * 256 + col];
        }
#pragma unroll
        for (int r = 0; r < 4; ++r)
            c2[r] = c2g[(size_t)(b0 + lgl * 4 + r) * 256 + hcolp];
    }
    __syncthreads();

    i32x4 wreg[16];
#pragma unroll
    for (int ks = 0; ks < 2; ++ks)
#pragma unroll
        for (int j = 0; j < 8; ++j)
            wreg[ks * 8 + j] = *(const i32x4*)&wp8B[(size_t)((ks * 64 + wid * 8 + j) * 64 + lane) * 16];

    float ssv[4];
#pragma unroll
    for (int g = 0; g < 4; ++g)
        ssv[g] = swB[g * 256 + hcolp] * (1.0f / 127.0f);

    const i32x4 zi = {0, 0, 0, 0};

    for (int t = t0; t < t1; ++t) {
        const int rb_ = t & 1;
        const signed char* hr = h2s[rb_];
        signed char* hw = h2s[rb_ ^ 1];

        u16x4 gxv[4];
#pragma unroll
        for (int g = 0; g < 4; ++g) {
            const int nt = wid * 8 + hfl * 4 + g;
            size_t addr = ((((size_t)bblk * TC + (t - t0)) * 64 + nt) * 16 + lc) * 8 + 4 * lgl;
            gxv[g] = *(const u16x4*)(gxc + addr);
        }

        i32x4 ia0[4], ia1[4];
#pragma unroll
        for (int g = 0; g < 4; ++g) { ia0[g] = zi; ia1[g] = zi; }
#pragma unroll
        for (int ks = 0; ks < 4; ++ks) {
            i32x4 afr = *(const i32x4*)&hr[lc * HP + ks * 64 + lg * 16];
#pragma unroll
            for (int g = 0; g < 4; ++g) {
                i32x4 w0 = (ks < 2) ? wreg[ks * 8 + g]
                         : *(const i32x4*)&wlds[ks - 2][wid * 8 + g][(size_t)lane * 16];
                ia0[g] = __builtin_amdgcn_mfma_i32_16x16x64_i8(afr, w0, ia0[g], 0, 0, 0);
                i32x4 w1 = (ks < 2) ? wreg[ks * 8 + 4 + g]
                         : *(const i32x4*)&wlds[ks - 2][wid * 8 + 4 + g][(size_t)lane * 16];
                ia1[g] = __builtin_amdgcn_mfma_i32_16x16x64_i8(afr, w1, ia1[g], 0, 0, 0);
            }
        }
        float gvv[4][4];
#pragma unroll
        for (int g = 0; g < 4; ++g)
#pragma unroll
            for (int r = 0; r < 4; ++r) {
                int v1  = __shfl(ia1[g][r], lane & 31);
                int sel = hfl ? v1 : ia0[g][r];
                gvv[g][r] = ssv[g] * (float)sel + bf2f(gxv[g][r]);
            }
#pragma unroll
        for (int r = 0; r < 4; ++r) {
            const int row = lgl * 4 + r;
            float cn = c2[r] * sigf(gvv[2][r]) + sigf(gvv[0][r]) * tanhf2(gvv[1][r]);
            float h  = tanhf2(cn) * sigf(gvv[3][r]);
            c2[r] = cn;
            hw[row * HP + hcolp] = q8(h);
        }
        BARL;
    }

    if (t1 < T_SZ) {
#pragma unroll
        for (int r = 0; r < 4; ++r)
            c2g[(size_t)(b0 + lgl * 4 + r) * 256 + hcolp] = c2[r];
        for (int i = tid; i < 8 * 256; i += NTHR) {
            int row = i >> 8, col = i & 255;
            h2p[(size_t)(b0 + row) * 256 + col] = h2s[0][row * HP + col];
        }
        return;
    }

    // ---- loss epilogue (final chunk): final h2 in h2s[0] (t1 even) ----
    const signed char* h2fin = h2s[0];
    for (int pp = tid; pp < 8 * VOCABN; pp += NTHR) {
        int row = pp / VOCABN, v = pp - row * VOCABN;
        float s = bd[v];
        for (int k = 0; k < HID; ++k)
            s += ((float)h2fin[row * HP + k] * (1.0f / 127.0f)) * Wd[k * VOCABN + v];
        logitb[row][v] = s;
    }
    __syncthreads();
    if (tid < 8) {
        float mx = -1e30f;
        for (int v = 0; v < VOCABN; ++v) mx = fmaxf(mx, logitb[tid][v]);
        float s = 0.f;
        for (int v = 0; v < VOCABN; ++v) s += __expf(logitb[tid][v] - mx);
        int lab = labels[b0 + tid];
        lossb[tid] = mx + __logf(s) - logitb[tid][lab];
    }
    __syncthreads();
    if (tid == 0) {
        float s = 0.f;
#pragma unroll
        for (int r = 0; r < 8; ++r) s += lossb[r];
        atomicAdd(out, s * (1.0f / (float)B_SZ));
    }
}

// ===================== launch =====================
extern "C" void kernel_launch(void* const* d_in, const int* in_sizes, int n_in,
                              void* d_out, int out_size, void* d_ws, size_t ws_size,
                              hipStream_t stream)
{
    (void)in_sizes; (void)n_in; (void)out_size;
    const int*   feat   = (const int*)d_in[0];
    const int*   labels = (const int*)d_in[1];
    const float* emb    = (const float*)d_in[2];
    const float* W1     = (const float*)d_in[3];
    const float* b1     = (const float*)d_in[4];
    const float* W2     = (const float*)d_in[5];
    const float* b2     = (const float*)d_in[6];
    const float* Wd     = (const float*)d_in[7];
    const float* bd     = (const float*)d_in[8];
    float* out = (float*)d_out;
    char* ws = (char*)d_ws;

    (void)hipMemsetAsync(d_out, 0, sizeof(float), stream);

    int TC = 2;
    {
        const int tcs[8] = {80, 40, 20, 16, 10, 8, 4, 2};
        for (int i = 0; i < 8; ++i)
            if (FIXED_WS + (size_t)tcs[i] * PER_TC <= ws_size) { TC = tcs[i]; break; }
    }

    signed char* wp8  = (signed char*)(ws + WP8_OFF);
    float*       eg2  = (float*)(ws + EG2_OFF);
    float*       sw   = (float*)(ws + SW_OFF);
    float*       c1g  = (float*)(ws + C1G_OFF);
    float*       c2g  = (float*)(ws + C2G_OFF);
    signed char* h2p  = (signed char*)(ws + H2P_OFF);
    signed char* h1c  = (signed char*)(ws + H1C_OFF);
    unsigned short* gxc = (unsigned short*)(ws + H1C_OFF + (size_t)TC * 524288ull);

    const signed char* wp8A = wp8;                       // W1h
    const signed char* wp8G = wp8 + 262144;              // W2x
    const signed char* wp8B = wp8 + 524288;              // W2h
    const float* swA = sw;
    const float* swG = sw + 1024;
    const float* swB = sw + 2048;

    prep_scale<<<(3 * 1024 + 255) / 256, 256, 0, stream>>>(W1, W2, sw);
    prep_pack<<<(3 * 4 * 64 * 64 + 255) / 256, 256, 0, stream>>>(W1, W2, sw, wp8);
    prep_eg2<<<(VOCABN * 256 + 255) / 256, 256, 0, stream>>>(emb, W1, b1, eg2);

    for (int t0 = 0; t0 < T_SZ; t0 += TC) {
        lstm_l1<<<256, NTHR, 0, stream>>>(feat, wp8A, swA, eg2, h1c, c1g, t0, TC);
        gx_gemm<<<256, NTHR, 0, stream>>>(h1c, wp8G, swG, b2, gxc, TC);
        lstm_l2<<<256, NTHR, 0, stream>>>(wp8B, swB, gxc, labels, Wd, bd,
                                          out, c2g, h2p, t0, TC);
    }
}